// Round 5
// baseline (111.387 us; speedup 1.0000x reference)
//
#include <hip/hip_runtime.h>
#include <math.h>

// Adder2D: out[n,co,h,w] = -sum_{ci,kh,kw} |x[n,ci,h+kh-1,w+kw-1] - w[co,ci,kh,kw]|
// x: [16,64,32,32] f32, w: [64,64,3,3] f32, out: [16,64,32,32] f32, pad=1 stride=1.
//
// R7: get w off the LDS pipe. R4 vs R6 A/B (16 vs 32 waves/CU, same per-CU
// work): identical duration -> CU-shared-pipe saturated, not latency.
// Model: 9 ds_read_b128 wave-uniform w-broadcasts per ci = ~28us/CU of LDS
// pipe, + 8-way-conflicted staging writes (addr === k+1 mod 4). Fix:
//   1) w read directly from global with wave-uniform indices -> s_load into
//      SGPRs (scalar L1, 9.2KB/block working set); inner op becomes
//      v_sub_f32(s,v) + v_add_f32 with abs modifier. ws LDS region deleted.
//   2) LDS row stride 36 -> 34 (even: b64 read alignment + conflict-free
//      reads preserved; write banks split into 2 residue classes -> 4-way).
// Block/grid unchanged from R6: 512 thr (128 outputs x 4 ci-groups), grid
// (4,16,16)=1024, LDS 21.8KB -> 4 blocks/CU.

#define N_   16
#define CI_  64
#define CO_  64
#define HW_  32
#define CG   4      // co per thread (= all of COB)
#define COB  4      // co per block
#define RG   8      // pixel rows per block
#define CIC  16     // ci planes staged per round
#define CPG  4      // ci planes computed per group per round
#define ROWS (RG + 2)
#define LW   34     // col0 = left halo, 1..32 = data, 33 = right halo

#define XS_WORDS (CIC * ROWS * LW)        // 5440 words = 21760 B

__global__ __launch_bounds__(512, 4) void adder2d_kernel(
    const float* __restrict__ x, const float* __restrict__ w,
    float* __restrict__ out)
{
    __shared__ __align__(16) float smem[XS_WORDS];
    float (*xs)[ROWS][LW] = (float (*)[ROWS][LW])smem;   // phase A
    float (*red)[128][8]  = (float (*)[128][8])smem;     // phase B: aliases xs
                                                         // 3*128*8 = 3072 <= 5440 ok

    const int tid = threadIdx.x;
    const int u   = tid & 15;            // col-pair: pixels at cols 2u, 2u+1
    const int rl  = (tid >> 4) & 7;      // pixel row within block
    const int cig = tid >> 7;            // ci group: 0..3
    const int r0  = blockIdx.x * RG;
    const int co0 = blockIdx.y * COB;
    const int n   = blockIdx.z;

    // ---- zero xs once: halo cols (0,33) and OOB row slots stay zero
    //      forever; staging rewrites only in-bounds data cols ----
    for (int i = tid; i < XS_WORDS / 4; i += 512)
        ((float4*)smem)[i] = float4{0.f, 0.f, 0.f, 0.f};

    float acc0[CG], acc1[CG];
#pragma unroll
    for (int j = 0; j < CG; ++j) { acc0[j] = 0.f; acc1[j] = 0.f; }

    const float* xn = x + (size_t)n * CI_ * HW_ * HW_;
    const float* wb = w + (size_t)co0 * (CI_ * 9);   // 4 co chunks, stride 576
    const int pbase = cig * CPG;

    for (int round = 0; round < CI_ / CIC; ++round) {
        const int cc0 = round * CIC;
        __syncthreads();   // protect LDS from previous round's readers
        // ---- stage CIC planes, rows r0-1..r0+8: 1280 float4 units ----
        for (int i = tid; i < CIC * ROWS * (HW_ / 4); i += 512) {
            int plane = i / (ROWS * (HW_ / 4));
            int rem   = i - plane * (ROWS * (HW_ / 4));
            int rr    = rem >> 3;
            int f4    = rem & 7;
            int gr    = r0 - 1 + rr;
            if ((unsigned)gr < HW_) {
                float4 v = ((const float4*)(xn + (size_t)(cc0 + plane) * HW_ * HW_
                                            + gr * HW_))[f4];
                float* dst = &xs[plane][rr][1 + 4 * f4];   // data cols start at 1
                dst[0] = v.x; dst[1] = v.y; dst[2] = v.z; dst[3] = v.w;
            }
        }
        __syncthreads();

#pragma unroll 2
        for (int cil = 0; cil < CPG; ++cil) {
            const int pl = pbase + cil;
            const int ci = cc0 + pl;

            // wave-uniform w loads -> s_load into SGPRs (scalar L1 cached):
            // wu[j][t] = w[co0+j][ci][t]
            float wu[CG][9];
#pragma unroll
            for (int j = 0; j < CG; ++j)
#pragma unroll
                for (int t = 0; t < 9; ++t)
                    wu[j][t] = wb[j * (CI_ * 9) + ci * 9 + t];

            // x patch for 2 pixels: rows rl..rl+2, storage cols 2u..2u+3
            // (= real cols 2u-1..2u+2, halos pre-zeroed). Aligned 2x b64.
            float4 xv[3];
#pragma unroll
            for (int kh = 0; kh < 3; ++kh) {
                const float* row = &xs[pl][rl + kh][2 * u];
                float2 lo = *(const float2*)&row[0];
                float2 hi = *(const float2*)&row[2];
                xv[kh] = float4{lo.x, lo.y, hi.x, hi.y};
            }

            // 144 VALU: 2 pix x 4 co x 9 taps, v_sub(s,v) + v_add(abs)
#pragma unroll
            for (int kh = 0; kh < 3; ++kh)
#pragma unroll
                for (int kw = 0; kw < 3; ++kw) {
                    const int t = kh * 3 + kw;
                    float xa = (kw == 0) ? xv[kh].x : ((kw == 1) ? xv[kh].y : xv[kh].z);
                    float xb = (kw == 0) ? xv[kh].y : ((kw == 1) ? xv[kh].z : xv[kh].w);
#pragma unroll
                    for (int j = 0; j < CG; ++j) {
                        acc0[j] += fabsf(xa - wu[j][t]);
                        acc1[j] += fabsf(xb - wu[j][t]);
                    }
                }
        }
    }

    // ---- combine the four ci-group partials (red aliases dead xs) ----
    __syncthreads();   // all xs readers done before overwrite
    if (cig != 0) {
        int t = tid & 127;
        *(float4*)&red[cig - 1][t][0] = float4{acc0[0], acc0[1], acc0[2], acc0[3]};
        *(float4*)&red[cig - 1][t][4] = float4{acc1[0], acc1[1], acc1[2], acc1[3]};
    }
    __syncthreads();
    if (cig == 0) {
#pragma unroll
        for (int g = 0; g < 3; ++g) {
            float4 ra = *(const float4*)&red[g][tid][0];
            float4 rb = *(const float4*)&red[g][tid][4];
            acc0[0] += ra.x; acc0[1] += ra.y; acc0[2] += ra.z; acc0[3] += ra.w;
            acc1[0] += rb.x; acc1[1] += rb.y; acc1[2] += rb.z; acc1[3] += rb.w;
        }
        float* op = out + (((size_t)n * CO_ + co0) * HW_ + (r0 + rl)) * HW_ + 2 * u;
#pragma unroll
        for (int j = 0; j < CG; ++j)
            *(float2*)&op[(size_t)j * HW_ * HW_] = float2{-acc0[j], -acc1[j]};
    }
}

extern "C" void kernel_launch(void* const* d_in, const int* in_sizes, int n_in,
                              void* d_out, int out_size, void* d_ws, size_t ws_size,
                              hipStream_t stream) {
    const float* x  = (const float*)d_in[0];
    const float* wp = (const float*)d_in[1];
    float* out      = (float*)d_out;
    dim3 grid(HW_ / RG, CO_ / COB, N_);   // (4, 16, 16) = 1024 blocks
    adder2d_kernel<<<grid, 512, 0, stream>>>(x, wp, out);
}

// Round 6
// 98.806 us; speedup vs baseline: 1.1273x; 1.1273x over previous
//
#include <hip/hip_runtime.h>
#include <math.h>

// Adder2D: out[n,co,h,w] = -sum_{ci,kh,kw} |x[n,ci,h+kh-1,w+kw-1] - w[co,ci,kh,kw]|
// x: [16,64,32,32] f32, w: [64,64,3,3] f32, out: [16,64,32,32] f32, pad=1 stride=1.
//
// R8: force w onto the scalar pipe. R7 post-mortem: SGPR_Count stayed 32 ->
// compiler emitted 36 per-lane global_load_dword/ci (threadIdx-derived cig
// defeats uniformity analysis), adding ~31us of VMEM pipe. Pipe ledger:
// VALU floor 15.4us, x-LDS ~10us, w-feed = the remaining ~35-40us on
// whichever pipe it rides (LDS-broadcast in R6, VMEM in R7). Fix: a tiny
// repack kernel writes w into d_ws as [cob][ci] slices (36 floats [j][t],
// padded to 64-float/256B slots); main kernel s_loads each slice via inline
// asm (s_load_dwordx16 x2 + x4) from an SGPR pointer built with
// readfirstlane(cig). Inner op: v_sub_f32(v,s,v) + v_add_f32(abs) -- w now
// costs zero LDS and zero VMEM. Everything else identical to R7.

#define N_   16
#define CI_  64
#define CO_  64
#define HW_  32
#define CG   4      // co per thread (= all of COB)
#define COB  4      // co per block
#define RG   8      // pixel rows per block
#define CIC  16     // ci planes staged per round
#define CPG  4      // ci planes computed per group per round
#define ROWS (RG + 2)
#define LW   34     // col0 = left halo, 1..32 = data, 33 = right halo
#define WSLICE 64   // floats per (cob,ci) w-slice slot (36 used, 256B aligned)

#define XS_WORDS (CIC * ROWS * LW)        // 5440 words = 21760 B

typedef __attribute__((ext_vector_type(16))) float f16v;
typedef __attribute__((ext_vector_type(4)))  float f4v;

// ---- repack: w[co][ci][t] -> wr[(co/4)*64+ci][ (co&3)*9 + t ], 64-f slots ----
__global__ void repack_w(const float* __restrict__ w, float* __restrict__ wr)
{
    int i  = blockIdx.x * 256 + threadIdx.x;   // 4096 = (co,ci) pairs
    int co = i >> 6;
    int ci = i & 63;
    float* dst = wr + (size_t)((co >> 2) * 64 + ci) * WSLICE + (co & 3) * 9;
    const float* src = w + (size_t)co * (CI_ * 9) + ci * 9;
#pragma unroll
    for (int t = 0; t < 9; ++t) dst[t] = src[t];
}

__device__ __forceinline__ float wget(const f16v& a, const f16v& b, const f4v& c, int idx)
{
    // idx is compile-time after full unroll
    return idx < 16 ? a[idx] : (idx < 32 ? b[idx - 16] : c[idx - 32]);
}

__global__ __launch_bounds__(512, 4) void adder2d_kernel(
    const float* __restrict__ x, const float* __restrict__ wr,
    float* __restrict__ out)
{
    __shared__ __align__(16) float smem[XS_WORDS];
    float (*xs)[ROWS][LW] = (float (*)[ROWS][LW])smem;   // phase A
    float (*red)[128][8]  = (float (*)[128][8])smem;     // phase B: aliases xs

    const int tid = threadIdx.x;
    const int u   = tid & 15;            // col-pair: pixels at cols 2u, 2u+1
    const int rl  = (tid >> 4) & 7;      // pixel row within block
    const int cig = tid >> 7;            // ci group: 0..3 (uniform per wave)
    const int r0  = blockIdx.x * RG;
    const int co0 = blockIdx.y * COB;
    const int n   = blockIdx.z;

    // wave-uniform ci-group index, provably scalar for the s_load pointer
    const int cigs = __builtin_amdgcn_readfirstlane(cig);
    const float* wrb = wr + (size_t)blockIdx.y * 64 * WSLICE;

    // ---- zero xs once: halo cols (0,33) and OOB row slots stay zero ----
    for (int i = tid; i < XS_WORDS / 4; i += 512)
        ((float4*)smem)[i] = float4{0.f, 0.f, 0.f, 0.f};

    float acc0[CG], acc1[CG];
#pragma unroll
    for (int j = 0; j < CG; ++j) { acc0[j] = 0.f; acc1[j] = 0.f; }

    const float* xn = x + (size_t)n * CI_ * HW_ * HW_;
    const int pbase = cig * CPG;

    for (int round = 0; round < CI_ / CIC; ++round) {
        const int cc0 = round * CIC;
        __syncthreads();   // protect LDS from previous round's readers
        // ---- stage CIC planes, rows r0-1..r0+8: 1280 float4 units ----
        for (int i = tid; i < CIC * ROWS * (HW_ / 4); i += 512) {
            int plane = i / (ROWS * (HW_ / 4));
            int rem   = i - plane * (ROWS * (HW_ / 4));
            int rr    = rem >> 3;
            int f4    = rem & 7;
            int gr    = r0 - 1 + rr;
            if ((unsigned)gr < HW_) {
                float4 v = ((const float4*)(xn + (size_t)(cc0 + plane) * HW_ * HW_
                                            + gr * HW_))[f4];
                float* dst = &xs[plane][rr][1 + 4 * f4];   // data cols start at 1
                dst[0] = v.x; dst[1] = v.y; dst[2] = v.z; dst[3] = v.w;
            }
        }
        __syncthreads();

#pragma unroll
        for (int cil = 0; cil < CPG; ++cil) {
            const int pl = pbase + cil;            // per-thread (LDS path)
            const int cis = cc0 + cigs * CPG + cil; // scalar (SMEM path)

            // ---- w slice (36 floats) via scalar loads into SGPRs ----
            const float* p = wrb + (size_t)cis * WSLICE;
            f16v wa, wb2; f4v wc;
            asm volatile(
                "s_load_dwordx16 %0, %3, 0x0\n\t"
                "s_load_dwordx16 %1, %3, 0x40\n\t"
                "s_load_dwordx4  %2, %3, 0x80\n\t"
                "s_waitcnt lgkmcnt(0)"
                : "=s"(wa), "=s"(wb2), "=s"(wc)
                : "s"(p));

            // x patch for 2 pixels: rows rl..rl+2, storage cols 2u..2u+3
            float4 xv[3];
#pragma unroll
            for (int kh = 0; kh < 3; ++kh) {
                const float* row = &xs[pl][rl + kh][2 * u];
                float2 lo = *(const float2*)&row[0];
                float2 hi = *(const float2*)&row[2];
                xv[kh] = float4{lo.x, lo.y, hi.x, hi.y};
            }

            // 144 VALU: 2 pix x 4 co x 9 taps, v_sub(v,s,v) + v_add(abs)
#pragma unroll
            for (int kh = 0; kh < 3; ++kh)
#pragma unroll
                for (int kw = 0; kw < 3; ++kw) {
                    const int t = kh * 3 + kw;
                    float xa = (kw == 0) ? xv[kh].x : ((kw == 1) ? xv[kh].y : xv[kh].z);
                    float xb = (kw == 0) ? xv[kh].y : ((kw == 1) ? xv[kh].z : xv[kh].w);
#pragma unroll
                    for (int j = 0; j < CG; ++j) {
                        float wjt = wget(wa, wb2, wc, j * 9 + t);
                        acc0[j] += fabsf(xa - wjt);
                        acc1[j] += fabsf(xb - wjt);
                    }
                }
        }
    }

    // ---- combine the four ci-group partials (red aliases dead xs) ----
    __syncthreads();   // all xs readers done before overwrite
    if (cig != 0) {
        int t = tid & 127;
        *(float4*)&red[cig - 1][t][0] = float4{acc0[0], acc0[1], acc0[2], acc0[3]};
        *(float4*)&red[cig - 1][t][4] = float4{acc1[0], acc1[1], acc1[2], acc1[3]};
    }
    __syncthreads();
    if (cig == 0) {
#pragma unroll
        for (int g = 0; g < 3; ++g) {
            float4 ra = *(const float4*)&red[g][tid][0];
            float4 rb = *(const float4*)&red[g][tid][4];
            acc0[0] += ra.x; acc0[1] += ra.y; acc0[2] += ra.z; acc0[3] += ra.w;
            acc1[0] += rb.x; acc1[1] += rb.y; acc1[2] += rb.z; acc1[3] += rb.w;
        }
        float* op = out + (((size_t)n * CO_ + co0) * HW_ + (r0 + rl)) * HW_ + 2 * u;
#pragma unroll
        for (int j = 0; j < CG; ++j)
            *(float2*)&op[(size_t)j * HW_ * HW_] = float2{-acc0[j], -acc1[j]};
    }
}

extern "C" void kernel_launch(void* const* d_in, const int* in_sizes, int n_in,
                              void* d_out, int out_size, void* d_ws, size_t ws_size,
                              hipStream_t stream) {
    const float* x  = (const float*)d_in[0];
    const float* wp = (const float*)d_in[1];
    float* out      = (float*)d_out;
    float* wr       = (float*)d_ws;   // 16*64*64*4 = 256 KiB used

    repack_w<<<dim3(16), 256, 0, stream>>>(wp, wr);
    dim3 grid(HW_ / RG, CO_ / COB, N_);   // (4, 16, 16) = 1024 blocks
    adder2d_kernel<<<grid, 512, 0, stream>>>(x, wr, out);
}